// Round 12
// baseline (21726.642 us; speedup 1.0000x reference)
//
#include <hip/hip_runtime.h>
#include <math.h>

#define T_STEPS 8192
#define I_DIM   64
#define H_DIM   2048
#define O_DIM   128
#define NBLK    256     // one block per CU; each owns 8 h-indices (32 gate rows)
#define NTHR    512     // 8 waves
// NSLOT = 2, parity-tagged: publish of h_t carries tag (t>>1)&1 in the
// mantissa LSB of every dword. Stale data (from t-2) has the opposite tag.
// No reset stores needed. Overwrite of h_{t-1} by h_{t+1} is safe: publishing
// h_{t+1} requires detecting all of h_t, which requires every CU to have
// passed barrier 1 of step t, i.e. finished reading h_{t-1}.

typedef float v4f __attribute__((ext_vector_type(4)));

__device__ __forceinline__ float sigmoid_f(float x) {
    return 1.0f / (1.0f + __expf(-x));
}
__device__ __forceinline__ float tanh_fast(float x) {
    // 2*sigmoid(2x)-1; saturates correctly for |x| large
    return 2.0f / (1.0f + __expf(-2.0f * x)) - 1.0f;
}

// DPP wave64 sum (VALU pipe, not LDS pipe). Lane 63 ends with the full sum.
template <int CTRL>
__device__ __forceinline__ float dpp_add(float v) {
    int s = __builtin_amdgcn_update_dpp(0, __builtin_bit_cast(int, v),
                                        CTRL, 0xF, 0xF, true);
    return v + __builtin_bit_cast(float, s);
}
__device__ __forceinline__ float wave_sum64_lane63(float v) {
    v = dpp_add<0x111>(v);  // row_shr:1
    v = dpp_add<0x112>(v);  // row_shr:2
    v = dpp_add<0x114>(v);  // row_shr:4
    v = dpp_add<0x118>(v);  // row_shr:8
    v = dpp_add<0x142>(v);  // row_bcast:15
    v = dpp_add<0x143>(v);  // row_bcast:31 -> lane63 = sum(0..63)
    return v;
}

__global__ void init_ws_kernel(unsigned int* Hbits) {
    int tid = blockIdx.x * blockDim.x + threadIdx.x;
    if (tid < 2 * H_DIM) {
        // slot 0 = h_0 = 0.0f, LSB=0 = tag for t=0 (consumer expects (0>>1)&1=0)
        // slot 1 = LSB=1 ("not ready": consumer of h_1 expects tag 0)
        Hbits[tid] = (tid < H_DIM) ? 0u : 0x7FC00001u;
    }
}

// Persistent LSTM recurrence — round-9 base (proven 2.34 us/step):
//  * strided 4x dword agent-scope atomic poll (lanes cover consecutive dwords)
//  * s_sleep(2) backoff (sleep(1) cost +46% FETCH / +7% dur — round 10)
//  * elementwise replicated in ALL waves' lanes<8 — keeps waves 1-7 busy
//    through the publish window (wave-0-only tail congested the LLC, r10/r11)
//  * publish = ONE coalesced 32B store from wave 0 lanes<8 (scattering the
//    publish was the round-4/5 8x-write regression — do not touch)
//  * DPP reduce (VALU), b128 LDS dot reads, 2 barriers
// Round-12 change: parity-tag LSB protocol, NSLOT=2, zero reset stores.
// Wave w: gate q = w>>1, joff = (w&1)*4; rows = q*2048 + cu*8 + joff + i
// Dot k-mapping: lane l covers k = m*256 + l*4 + j -> one ds_read_b128 per m.
__global__ __launch_bounds__(NTHR, 2) void lstm_persistent(
    const float* __restrict__ x,     // [T, 64]
    const float* __restrict__ Wih,   // [8192, 64]
    const float* __restrict__ Whh,   // [8192, 2048]
    const float* __restrict__ bih,   // [8192]
    const float* __restrict__ bhh,   // [8192]
    unsigned int* __restrict__ Hbits)// [2][2048] in ws (float bits, LSB = tag)
{
    const int cu   = blockIdx.x;
    const int tid  = threadIdx.x;
    const int w    = tid >> 6;
    const int lane = tid & 63;

    __shared__ float hbuf[H_DIM];   // 8 KB, hbuf[k] = h[k]
    __shared__ float xbuf[I_DIM];
    __shared__ float gbuf[32];      // gbuf[g*8 + j] = gate-g preact of h-sub j

    const int q    = w >> 1;
    const int joff = (w & 1) * 4;
    const int row0 = q * H_DIM + cu * 8 + joff;

    // ---- one-time: W_hh fragment into registers ----
    // wreg[i][m] = W[row0+i][m*256 + lane*4 .. +3]   (coalesced 16B loads)
    v4f wreg[4][8];
#pragma unroll
    for (int i = 0; i < 4; i++) {
        const float* p = Whh + (size_t)(row0 + i) * H_DIM + lane * 4;
#pragma unroll
        for (int m = 0; m < 8; m++)
            wreg[i][m] = *(const v4f*)(p + m * 256);
    }
    // x-part: lane handles row (row0 + (lane>>4)), k-range (lane&15)*4 .. +4
    float xw[4];
    {
        const int xr = row0 + (lane >> 4);
        const float* p = Wih + (size_t)xr * I_DIM + (lane & 15) * 4;
#pragma unroll
        for (int m = 0; m < 4; m++) xw[m] = p[m];
    }
    // biases: every wave keeps them (elementwise phase is replicated per wave)
    float bias[4] = {0.f, 0.f, 0.f, 0.f};
    if (lane < 8) {
#pragma unroll
        for (int g = 0; g < 4; g++) {
            int r = g * H_DIM + cu * 8 + lane;
            bias[g] = bih[r] + bhh[r];
        }
    }
    float cstate = 0.0f;   // replicated in lanes 0..7 of every wave

    for (int t = 0; t < T_STEPS; t++) {
        const unsigned int tg_r = (unsigned int)((t >> 1) & 1);        // tag of h_t
        const unsigned int tg_w = (unsigned int)(((t + 1) >> 1) & 1);  // tag of h_{t+1}
        const int slot_r = t & 1;
        const int slot_w = (t + 1) & 1;

        // hoist the independent x load above the spin
        float xv_own = (tid < I_DIM) ? x[(size_t)t * I_DIM + tid] : 0.0f;

        // ---- 1. poll h_t (LSB tag = ready flag) and stage into LDS ----
        {
            const unsigned int* Hr = Hbits + slot_r * H_DIM;
            unsigned int u0, u1, u2, u3;
            for (;;) {
                u0 = __hip_atomic_load(Hr + tid,             __ATOMIC_RELAXED, __HIP_MEMORY_SCOPE_AGENT);
                u1 = __hip_atomic_load(Hr + tid + 1 * NTHR,  __ATOMIC_RELAXED, __HIP_MEMORY_SCOPE_AGENT);
                u2 = __hip_atomic_load(Hr + tid + 2 * NTHR,  __ATOMIC_RELAXED, __HIP_MEMORY_SCOPE_AGENT);
                u3 = __hip_atomic_load(Hr + tid + 3 * NTHR,  __ATOMIC_RELAXED, __HIP_MEMORY_SCOPE_AGENT);
                bool miss = ((u0 & 1) != tg_r) | ((u1 & 1) != tg_r) |
                            ((u2 & 1) != tg_r) | ((u3 & 1) != tg_r);
                if (!miss) break;
                __builtin_amdgcn_s_sleep(2);
            }
            hbuf[tid]            = __uint_as_float(u0);
            hbuf[tid + 1 * NTHR] = __uint_as_float(u1);
            hbuf[tid + 2 * NTHR] = __uint_as_float(u2);
            hbuf[tid + 3 * NTHR] = __uint_as_float(u3);
            if (tid < I_DIM) xbuf[tid] = xv_own;
        }
        __syncthreads();   // barrier 1: hbuf/xbuf ready

        // ---- 2. dot products: 4 rows per wave, 8 x (ds_read_b128 + packed FMA) ----
        v4f av0 = {0.f,0.f,0.f,0.f}, av1 = {0.f,0.f,0.f,0.f};
        v4f av2 = {0.f,0.f,0.f,0.f}, av3 = {0.f,0.f,0.f,0.f};
#pragma unroll
        for (int m = 0; m < 8; m++) {
            v4f hv = *(const v4f*)&hbuf[m * 256 + lane * 4];
            av0 += wreg[0][m] * hv;
            av1 += wreg[1][m] * hv;
            av2 += wreg[2][m] * hv;
            av3 += wreg[3][m] * hv;
        }
        float acc0 = (av0[0] + av0[1]) + (av0[2] + av0[3]);
        float acc1 = (av1[0] + av1[1]) + (av1[2] + av1[3]);
        float acc2 = (av2[0] + av2[1]) + (av2[2] + av2[3]);
        float acc3 = (av3[0] + av3[1]) + (av3[2] + av3[3]);
        {   // fold in W_ih * x_t
            float xp = 0.f;
            const int b = (lane & 15) * 4;
#pragma unroll
            for (int m = 0; m < 4; m++) xp += xw[m] * xbuf[b + m];
            const int sel = lane >> 4;
            acc0 += (sel == 0) ? xp : 0.0f;
            acc1 += (sel == 1) ? xp : 0.0f;
            acc2 += (sel == 2) ? xp : 0.0f;
            acc3 += (sel == 3) ? xp : 0.0f;
        }
        // ---- 3. DPP reduce (VALU pipe); lane 63 posts to gbuf ----
        acc0 = wave_sum64_lane63(acc0);
        acc1 = wave_sum64_lane63(acc1);
        acc2 = wave_sum64_lane63(acc2);
        acc3 = wave_sum64_lane63(acc3);
        if (lane == 63) {
            gbuf[q * 8 + joff + 0] = acc0;
            gbuf[q * 8 + joff + 1] = acc1;
            gbuf[q * 8 + joff + 2] = acc2;
            gbuf[q * 8 + joff + 3] = acc3;
        }
        __syncthreads();   // barrier 2: gbuf ready; orders hbuf(t) reads
                           // before hbuf(t+1) staging writes

        // ---- 4. elementwise cell update, replicated in every wave (lanes 0..7);
        //         wave 0 publishes — ONE coalesced 32B tagged store ----
        if (lane < 8) {
            float iv = sigmoid_f(gbuf[0 * 8 + lane] + bias[0]);
            float fv = sigmoid_f(gbuf[1 * 8 + lane] + bias[1]);
            float gv = tanh_fast(gbuf[2 * 8 + lane] + bias[2]);
            float ov = sigmoid_f(gbuf[3 * 8 + lane] + bias[3]);
            cstate = fv * cstate + iv * gv;
            float hval = ov * tanh_fast(cstate);
            if (w == 0) {
                unsigned int bits = (__float_as_uint(hval) & ~1u) | tg_w;
                __hip_atomic_store(Hbits + slot_w * H_DIM + cu * 8 + lane, bits,
                                   __ATOMIC_RELAXED, __HIP_MEMORY_SCOPE_AGENT);
            }
        }
    }
}

// Final linear: out[o] = h_T . W_lin[o,:] + b_lin[o].  One wave per output.
// h_T lives in slot (T_STEPS & 1) == 0 (tag LSBs perturb h by <=2^-24 — fine).
__global__ void final_linear(const float* __restrict__ hT,
                             const float* __restrict__ Wlin,
                             const float* __restrict__ blin,
                             float* __restrict__ out)
{
    int gw   = (blockIdx.x * blockDim.x + threadIdx.x) >> 6;
    int lane = threadIdx.x & 63;
    if (gw < O_DIM) {
        const float* wp = Wlin + (size_t)gw * H_DIM;
        float s = 0.f;
        for (int k = lane; k < H_DIM; k += 64)
            s += wp[k] * hT[k];
#pragma unroll
        for (int off = 32; off; off >>= 1) s += __shfl_xor(s, off, 64);
        if (lane == 0) out[gw] = s + blin[gw];
    }
}

extern "C" void kernel_launch(void* const* d_in, const int* in_sizes, int n_in,
                              void* d_out, int out_size, void* d_ws, size_t ws_size,
                              hipStream_t stream)
{
    const float* x    = (const float*)d_in[0];
    const float* Wih  = (const float*)d_in[1];
    const float* Whh  = (const float*)d_in[2];
    const float* bih  = (const float*)d_in[3];
    const float* bhh  = (const float*)d_in[4];
    const float* Wlin = (const float*)d_in[5];
    const float* blin = (const float*)d_in[6];
    float* out = (float*)d_out;

    unsigned int* Hbits = (unsigned int*)d_ws;

    hipLaunchKernelGGL(init_ws_kernel, dim3((2 * H_DIM + 255) / 256), dim3(256),
                       0, stream, Hbits);

    void* args[] = { (void*)&x, (void*)&Wih, (void*)&Whh, (void*)&bih, (void*)&bhh,
                     (void*)&Hbits };
    (void)hipLaunchCooperativeKernel(reinterpret_cast<void*>(lstm_persistent),
                                     dim3(NBLK), dim3(NTHR), args, 0, stream);

    // h_T is in slot (T_STEPS & 1) == 0
    hipLaunchKernelGGL(final_linear, dim3(32), dim3(256), 0, stream,
                       (const float*)Hbits, Wlin, blin, out);
}